// Round 20
// baseline (191.636 us; speedup 1.0000x reference)
//
#include <hip/hip_runtime.h>
#include <hip/hip_bf16.h>

#define NT 768
#define ND 256
#define PD 128
#define NH 8
#define DH 32
#define NPAIR 589824   // 768*768

// workspace offsets (floats)
#define WS_X     0
#define WS_Q     196608
#define WS_K     393216
#define WS_V     589824
#define WS_GATE  786432
#define WS_AOUT  983040
#define WS_BIAS  1179648   // bias layout: [i][h][j] = (i*8+h)*768+j
#define WS_BFT   5898240   // 2048 bf16 = 4096 B = 1024 floats: B-table [16 cols][128 k]
#define WS_C01   5899264   // = WS_BFT + 1024
// total = 5899280 floats = 23.6 MB

typedef float f32x4 __attribute__((ext_vector_type(4)));
using bf16x8 = __attribute__((ext_vector_type(8))) short;   // 8 bf16 (4 VGPR)
using f32x4v = __attribute__((ext_vector_type(4))) float;

// compiler-fusable bf16 cast (emits v_cvt_pk_bf16_f32 for pairs — m240)
static __device__ __forceinline__ short f2bf(float f) {
  union { __hip_bfloat16 h; short s; } u;
  u.h = __float2bfloat16(f);
  return u.s;
}
static __device__ __forceinline__ unsigned long long pack4bf(f32x4 p) {
  return (unsigned long long)(unsigned short)f2bf(p.x) |
         ((unsigned long long)(unsigned short)f2bf(p.y) << 16) |
         ((unsigned long long)(unsigned short)f2bf(p.z) << 32) |
         ((unsigned long long)(unsigned short)f2bf(p.w) << 48);
}

// ---------------- K0: precompute bf16 B-table + c0/c1 (one block, simple) ----------------
__global__ __launch_bounds__(128) void k_prep(const float* __restrict__ lnw,
                                              const float* __restrict__ lnb,
                                              const float* __restrict__ wb,
                                              unsigned short* __restrict__ bfT,
                                              float* __restrict__ c01) {
  int t = threadIdx.x;                 // one thread per k (128)
  float lw = lnw[t], lb = lnb[t];
#pragma unroll
  for (int col = 0; col < 16; ++col) {
    float v = (col < 8) ? lw * wb[t * 8 + col] : (col == 8 ? 1.f : 0.f);
    bfT[col * 128 + t] = (unsigned short)f2bf(v);
  }
  __shared__ float r0[8][128], r1[8][128];
#pragma unroll
  for (int h = 0; h < 8; ++h) {
    float wv = wb[t * 8 + h];
    r0[h][t] = lb * wv;
    r1[h][t] = lw * wv;
  }
  __syncthreads();
  if (t < 16) {
    int h = t & 7;
    const float* src = (t < 8) ? r0[h] : r1[h];
    float s = 0.f;
    for (int k = 0; k < 128; ++k) s += src[k];
    c01[(t < 8) ? h : 8 + h] = s;
  }
}

// ---------------- K2: LN(node) fused + x @ [w_qkv | w_g] -> q,k,v + gate ----------------
__global__ __launch_bounds__(256) void k_qkvg(const float* __restrict__ node,
                                              const float* __restrict__ lnw,
                                              const float* __restrict__ lnb,
                                              const float* __restrict__ wqkv,
                                              const float* __restrict__ wg,
                                              const float* __restrict__ bg,
                                              float* __restrict__ ws) {
  __shared__ __align__(16) float As[16 * 64];
  __shared__ __align__(16) float Bs[16 * 64];
  __shared__ float MU[64], RS[64];
  __shared__ float LW[256], LB[256];
  int n0 = blockIdx.x * 64, i0 = blockIdx.y * 64, t = threadIdx.x;
  bool isg = (n0 >= 768);
  const float* W = isg ? wg : wqkv;
  int ldb = isg ? 256 : 768;
  int nc0 = isg ? n0 - 768 : n0;
  int tm = t >> 4, tn = t & 15;
  int sm = t >> 2, sk = (t & 3) * 4;
  int bk = t >> 4, bn = (t & 15) * 4;

  LW[t] = lnw[t];
  LB[t] = lnb[t];
  {
    int r = t >> 2, q = t & 3;
    const float4* src = (const float4*)&node[(size_t)(i0 + r) * 256 + q * 64];
    float s1 = 0.f, s2 = 0.f;
#pragma unroll
    for (int c = 0; c < 16; ++c) {
      float4 p = src[c];
      s1 += p.x + p.y + p.z + p.w;
      s2 = fmaf(p.x, p.x, fmaf(p.y, p.y, fmaf(p.z, p.z, fmaf(p.w, p.w, s2))));
    }
    s1 += __shfl_xor(s1, 1); s1 += __shfl_xor(s1, 2);
    s2 += __shfl_xor(s2, 1); s2 += __shfl_xor(s2, 2);
    if (q == 0) {
      float mu = s1 * (1.f / 256.f);
      float var = s2 * (1.f / 256.f) - mu * mu;
      MU[r] = mu;
      RS[r] = rsqrtf(var + 1e-5f);
    }
  }
  __syncthreads();

  float acc[4][4] = {{0.f}};
  for (int k0 = 0; k0 < 256; k0 += 16) {
    float4 av = *(const float4*)&node[(size_t)(i0 + sm) * 256 + k0 + sk];
    float4 bv = *(const float4*)&W[(size_t)(k0 + bk) * ldb + nc0 + bn];
    __syncthreads();
    {
      float mu = MU[sm], rs = RS[sm];
      av.x = (av.x - mu) * rs * LW[k0 + sk + 0] + LB[k0 + sk + 0];
      av.y = (av.y - mu) * rs * LW[k0 + sk + 1] + LB[k0 + sk + 1];
      av.z = (av.z - mu) * rs * LW[k0 + sk + 2] + LB[k0 + sk + 2];
      av.w = (av.w - mu) * rs * LW[k0 + sk + 3] + LB[k0 + sk + 3];
    }
    As[(sk + 0) * 64 + sm] = av.x; As[(sk + 1) * 64 + sm] = av.y;
    As[(sk + 2) * 64 + sm] = av.z; As[(sk + 3) * 64 + sm] = av.w;
    *(float4*)&Bs[bk * 64 + bn] = bv;
    __syncthreads();
#pragma unroll
    for (int kk = 0; kk < 16; ++kk) {
      float4 a4 = *(float4*)&As[kk * 64 + tm * 4];
      float4 b4 = *(float4*)&Bs[kk * 64 + tn * 4];
      float ar[4] = {a4.x, a4.y, a4.z, a4.w};
      float br[4] = {b4.x, b4.y, b4.z, b4.w};
#pragma unroll
      for (int ii = 0; ii < 4; ++ii)
#pragma unroll
        for (int jj = 0; jj < 4; ++jj) acc[ii][jj] = fmaf(ar[ii], br[jj], acc[ii][jj]);
    }
  }
#pragma unroll
  for (int ii = 0; ii < 4; ++ii) {
    int i = i0 + tm * 4 + ii;
#pragma unroll
    for (int jj = 0; jj < 4; ++jj) {
      int o = n0 + tn * 4 + jj;
      float val = acc[ii][jj];
      if (!isg) {
        int which = o >> 8, inner = o & 255, h = inner >> 5, d = inner & 31;
        float* dst = ws + (which == 0 ? WS_Q : (which == 1 ? WS_K : WS_V));
        float sc = (which == 0) ? 0.17677669529663687f : 1.f;  // 1/sqrt(32) on q
        dst[(h * NT + i) * DH + d] = val * sc;
      } else {
        int inner = nc0 + tn * 4 + jj;
        val += bg[inner];
        ws[WS_GATE + i * ND + inner] = 1.f / (1.f + __expf(-val));
      }
    }
  }
}

// ---------------- K3: fused LN(pair) @ w_bias + mask fold -> bias [i][h][j] ----------------
// R19 structure + 2-deep register prefetch (buf0/buf1, fully unrolled tiles):
// 16KB/wave in flight instead of 8KB — covers the ~600cyc/tile exposed HBM
// latency per Little's law. Staging/MFMA/epilogue unchanged.
#define PB_STAGE(BUF)                                                          \
  _Pragma("unroll")                                                            \
  for (int i = 0; i < 8; ++i) {                                                \
    f32x4 p = BUF[i];                                                          \
    int row = i * 2 + ldrow;                                                   \
    unsigned long long pk = pack4bf(p);                                        \
    unsigned long long pk2 = pack4bf(p * p);                                   \
    char* base = (char*)at + row * 256 + ((gwr ^ row) * 16) + half * 8;        \
    *(unsigned long long*)base = pk;                                           \
    *(unsigned long long*)(base + 16 * 256) = pk2;                             \
  }

#define PB_LOAD(BUF, ROW0)                                                     \
  _Pragma("unroll")                                                            \
  for (int i = 0; i < 8; ++i)                                                  \
    BUF[i] = *(const f32x4*)(pf + (ROW0) * 128 + i * 256 + l * 4);

#define PB_COMPUTE(TILE)                                                       \
  {                                                                            \
    size_t r0 = wrow0 + (TILE) * 16;                                           \
    f32x4v acc = {0.f, 0.f, 0.f, 0.f};                                         \
    f32x4v acc2 = {0.f, 0.f, 0.f, 0.f};                                        \
    _Pragma("unroll")                                                          \
    for (int c = 0; c < 4; ++c) {                                              \
      const char* rb = (const char*)at + col * 256 + (((c * 4 + kg) ^ col) * 16); \
      bf16x8 afrag = *(const bf16x8*)rb;                                       \
      bf16x8 afrag2 = *(const bf16x8*)(rb + 16 * 256);                         \
      acc = __builtin_amdgcn_mfma_f32_16x16x32_bf16(afrag, bfrag[c], acc, 0, 0, 0);   \
      acc2 = __builtin_amdgcn_mfma_f32_16x16x32_bf16(afrag2, bfrag[c], acc2, 0, 0, 0);\
    }                                                                          \
    int4 mk4 = *(const int4*)&mask[r0 + kg * 4];                               \
    float4 ov;                                                                 \
    int mks[4] = {mk4.x, mk4.y, mk4.z, mk4.w};                                 \
    _Pragma("unroll")                                                          \
    for (int rg = 0; rg < 4; ++rg) {                                           \
      float s1 = __shfl(acc[rg], srcl);                                        \
      float s2 = __shfl(acc2[rg], srcl);                                       \
      float mu = s1 * (1.f / 128.f);                                           \
      float var = s2 * (1.f / 128.f) - mu * mu;                                \
      float rs = rsqrtf(var + 1e-5f);                                          \
      float bv = rs * (acc[rg] - mu * c1p) + c0p;                              \
      (&ov.x)[rg] = mks[rg] ? bv : -1e30f;                                     \
    }                                                                          \
    if (col < 8) {                                                             \
      size_t i_idx = r0 / 768;                                                 \
      int j0 = (int)(r0 % 768) + kg * 4;                                       \
      *(float4*)&bias_out[(i_idx * 8 + col) * 768 + j0] = ov;                  \
    }                                                                          \
  }

__global__ __launch_bounds__(256) void k_pair_bias(const float* __restrict__ pf,
                                                   const int* __restrict__ mask,
                                                   const unsigned short* __restrict__ bfT,
                                                   const float* __restrict__ c01,
                                                   float* __restrict__ bias_out) {
  __shared__ __align__(16) unsigned short AT[4][2 * 16 * 128];  // 8KB per wave (A | A2)
  int t = threadIdx.x;
  int w = t >> 6, l = t & 63;
  int col = l & 15, kg = l >> 4;
  int half = l & 1;
  int ldrow = l >> 5;            // row parity within a load instr
  int gwr = (l & 31) >> 1;       // write granule 0..15

  bf16x8 bfrag[4];
#pragma unroll
  for (int c = 0; c < 4; ++c)
    bfrag[c] = *(const bf16x8*)(bfT + col * 128 + c * 32 + kg * 8);
  float c0p = (col < 8) ? c01[col] : 0.f;
  float c1p = (col < 8) ? c01[8 + col] : 0.f;

  unsigned short* at = AT[w];
  size_t wrow0 = ((size_t)blockIdx.x * 4 + w) * 64;   // this wave's 64 rows
  int srcl = (l & 48) | 8;                            // s1/s2 holder lane in group

  // 2-deep prefetch: T0 -> buf0, T1 -> buf1
  f32x4 buf0[8], buf1[8];
  PB_LOAD(buf0, wrow0)
  PB_LOAD(buf1, wrow0 + 16)

  // tile 0: stage buf0, refill buf0 with T2, compute
  PB_STAGE(buf0)
  PB_LOAD(buf0, wrow0 + 32)
  PB_COMPUTE(0)
  // tile 1: stage buf1, refill buf1 with T3, compute
  PB_STAGE(buf1)
  PB_LOAD(buf1, wrow0 + 48)
  PB_COMPUTE(1)
  // tile 2: stage buf0, compute
  PB_STAGE(buf0)
  PB_COMPUTE(2)
  // tile 3: stage buf1, compute
  PB_STAGE(buf1)
  PB_COMPUTE(3)
}

// ---------------- K4: per (head, 8-row tile) attention + gate ----------------
// v4 (R16-verified): SIM-LDS structure, float4 SIM reads + 4 accumulators.
__global__ __launch_bounds__(256) void k_attn(const float* __restrict__ q,
                                              const float* __restrict__ k,
                                              const float* __restrict__ v,
                                              const float* __restrict__ gate,
                                              const float* __restrict__ bias,
                                              float* __restrict__ aout) {
  __shared__ __align__(16) float SIM[8 * 772];
  __shared__ __align__(16) float QS[256];
  int i0 = blockIdx.x * 8, h = blockIdx.y, t = threadIdx.x;
  int tr = t >> 5, tc = t & 31;
  QS[t] = q[((size_t)h * NT + i0 + tr) * DH + tc];   // t == tr*32+tc
  float4 qr[8];
#pragma unroll
  for (int e = 0; e < 8; ++e) qr[e] = *(float4*)&QS[tr * 32 + e * 4];
  const float* Kh = k + (size_t)h * NT * DH;
  const float* Vh = v + (size_t)h * NT * DH;
  const float* brow = bias + ((size_t)(i0 + tr) * 8 + h) * 768;   // [i][h][j]
  float sv[24];
  float mx = -3.4e38f;
#pragma unroll
  for (int it = 0; it < 24; ++it) {
    int j = it * 32 + tc;
    const float4* kr = (const float4*)(Kh + j * DH);
    float s = 0.f;
#pragma unroll
    for (int e = 0; e < 8; ++e) {
      float4 kv = kr[e];
      s += qr[e].x * kv.x + qr[e].y * kv.y + qr[e].z * kv.z + qr[e].w * kv.w;
    }
    s += brow[j];                     // q pre-scaled; bias carries mask fold
    sv[it] = s;
    mx = fmaxf(mx, s);
  }
#pragma unroll
  for (int m = 1; m < 32; m <<= 1) mx = fmaxf(mx, __shfl_xor(mx, m));
  float sum = 0.f;
#pragma unroll
  for (int it = 0; it < 24; ++it) {
    float p = __expf(sv[it] - mx);
    SIM[tr * 772 + it * 32 + tc] = p;
    sum += p;
  }
#pragma unroll
  for (int m = 1; m < 32; m <<= 1) sum += __shfl_xor(sum, m);
  float inv = 1.f / sum;
  __syncthreads();
  float acc0 = 0.f, acc1 = 0.f, acc2 = 0.f, acc3 = 0.f;
#pragma unroll 4
  for (int j4 = 0; j4 < NT; j4 += 4) {
    float4 p4 = *(float4*)&SIM[tr * 772 + j4];   // b128 broadcast (2 addrs/wave)
    acc0 = fmaf(p4.x, Vh[(j4 + 0) * DH + tc], acc0);
    acc1 = fmaf(p4.y, Vh[(j4 + 1) * DH + tc], acc1);
    acc2 = fmaf(p4.z, Vh[(j4 + 2) * DH + tc], acc2);
    acc3 = fmaf(p4.w, Vh[(j4 + 3) * DH + tc], acc3);
  }
  float acc = ((acc0 + acc1) + (acc2 + acc3)) * inv;
  int i = i0 + tr;
  float gg = gate[i * ND + h * DH + tc];
  aout[i * ND + h * DH + tc] = acc * gg;
}

// ---------------- K5: aout @ w_out + b_out -> fp32 output ----------------
__global__ __launch_bounds__(256) void k_proj(const float* __restrict__ a,
                                              const float* __restrict__ w,
                                              const float* __restrict__ b,
                                              float* __restrict__ out) {
  __shared__ __align__(16) float As[16 * 64];
  __shared__ __align__(16) float Bs[16 * 64];
  int n0 = blockIdx.x * 64, i0 = blockIdx.y * 64, t = threadIdx.x;
  int tm = t >> 4, tn = t & 15;
  int sm = t >> 2, sk = (t & 3) * 4;
  int bk = t >> 4, bn = (t & 15) * 4;
  float acc[4][4] = {{0.f}};
  for (int k0 = 0; k0 < 256; k0 += 16) {
    float4 av = *(const float4*)&a[(i0 + sm) * 256 + k0 + sk];
    float4 bv = *(const float4*)&w[(k0 + bk) * 256 + n0 + bn];
    __syncthreads();
    As[(sk + 0) * 64 + sm] = av.x; As[(sk + 1) * 64 + sm] = av.y;
    As[(sk + 2) * 64 + sm] = av.z; As[(sk + 3) * 64 + sm] = av.w;
    *(float4*)&Bs[bk * 64 + bn] = bv;
    __syncthreads();
#pragma unroll
    for (int kk = 0; kk < 16; ++kk) {
      float4 a4 = *(float4*)&As[kk * 64 + tm * 4];
      float4 b4 = *(float4*)&Bs[kk * 64 + tn * 4];
      float ar[4] = {a4.x, a4.y, a4.z, a4.w};
      float br[4] = {b4.x, b4.y, b4.z, b4.w};
#pragma unroll
      for (int ii = 0; ii < 4; ++ii)
#pragma unroll
        for (int jj = 0; jj < 4; ++jj) acc[ii][jj] = fmaf(ar[ii], br[jj], acc[ii][jj]);
    }
  }
#pragma unroll
  for (int ii = 0; ii < 4; ++ii) {
    int i = i0 + tm * 4 + ii;
#pragma unroll
    for (int jj = 0; jj < 4; ++jj) {
      int o = n0 + tn * 4 + jj;
      out[i * 256 + o] = acc[ii][jj] + b[o];
    }
  }
}

extern "C" void kernel_launch(void* const* d_in, const int* in_sizes, int n_in,
                              void* d_out, int out_size, void* d_ws, size_t ws_size,
                              hipStream_t stream) {
  const float* node   = (const float*)d_in[0];
  const float* pair   = (const float*)d_in[1];
  const int*   mask   = (const int*)d_in[2];
  const float* ln_nw  = (const float*)d_in[3];
  const float* ln_nb  = (const float*)d_in[4];
  const float* ln_pw  = (const float*)d_in[5];
  const float* ln_pb  = (const float*)d_in[6];
  const float* w_qkv  = (const float*)d_in[7];
  const float* w_g    = (const float*)d_in[8];
  const float* b_g    = (const float*)d_in[9];
  const float* w_bias = (const float*)d_in[10];
  const float* w_out  = (const float*)d_in[11];
  const float* b_out  = (const float*)d_in[12];
  float* ws = (float*)d_ws;
  float* out = (float*)d_out;
  unsigned short* bfT = (unsigned short*)(ws + WS_BFT);

  k_prep<<<1, 128, 0, stream>>>(ln_pw, ln_pb, w_bias, bfT, ws + WS_C01);
  k_pair_bias<<<NPAIR / 256, 256, 0, stream>>>(pair, mask, bfT, ws + WS_C01,
                                               ws + WS_BIAS);
  k_qkvg<<<dim3(16, 12), 256, 0, stream>>>(node, ln_nw, ln_nb, w_qkv, w_g, b_g, ws);
  k_attn<<<dim3(96, 8), 256, 0, stream>>>(ws + WS_Q, ws + WS_K, ws + WS_V,
                                          ws + WS_GATE, ws + WS_BIAS, ws + WS_AOUT);
  k_proj<<<dim3(4, 12), 256, 0, stream>>>(ws + WS_AOUT, w_out, b_out, out);
}

// Round 21
// 168.241 us; speedup vs baseline: 1.1391x; 1.1391x over previous
//
#include <hip/hip_runtime.h>
#include <hip/hip_bf16.h>

#define NT 768
#define ND 256
#define PD 128
#define NH 8
#define DH 32
#define NPAIR 589824   // 768*768

// workspace offsets (floats)
#define WS_X     0
#define WS_Q     196608
#define WS_K     393216
#define WS_V     589824
#define WS_GATE  786432
#define WS_AOUT  983040
#define WS_BIAS  1179648   // bias layout: [i][h][j] = (i*8+h)*768+j
// total = 1179648 + 8*589824 = 5898240 floats = 23.6 MB

#define QKVG_BLOCKS 192    // 16 x 12
#define PAIR_BLOCKS 2304   // NPAIR/256

typedef float f32x4 __attribute__((ext_vector_type(4)));
using bf16x8 = __attribute__((ext_vector_type(8))) short;   // 8 bf16 (4 VGPR)
using f32x4v = __attribute__((ext_vector_type(4))) float;

// compiler-fusable bf16 cast (emits v_cvt_pk_bf16_f32 for pairs — m240)
static __device__ __forceinline__ short f2bf(float f) {
  union { __hip_bfloat16 h; short s; } u;
  u.h = __float2bfloat16(f);
  return u.s;
}
static __device__ __forceinline__ unsigned long long pack4bf(f32x4 p) {
  return (unsigned long long)(unsigned short)f2bf(p.x) |
         ((unsigned long long)(unsigned short)f2bf(p.y) << 16) |
         ((unsigned long long)(unsigned short)f2bf(p.z) << 32) |
         ((unsigned long long)(unsigned short)f2bf(p.w) << 48);
}

// ---------------- K1 fused: [qkvg blocks 0..191] + [pair_bias blocks 192..2495] ----------------
// qkvg body = R19-verified; pair body = R16-verified (in-wave B-frag build,
// 1-deep prefetch, dual-plane LDS, dual MFMA). Independent work overlapped in
// one launch; LDS = 32KB carved union.
__global__ __launch_bounds__(256) void k_fused(
    const float* __restrict__ node, const float* __restrict__ nlnw,
    const float* __restrict__ nlnb, const float* __restrict__ wqkv,
    const float* __restrict__ wg, const float* __restrict__ bg,
    float* __restrict__ ws,
    const float* __restrict__ pf, const int* __restrict__ mask,
    const float* __restrict__ plnw, const float* __restrict__ plnb,
    const float* __restrict__ wb, float* __restrict__ bias_out) {
  __shared__ __align__(16) char SMEM[32768];
  int t = threadIdx.x;

  if (blockIdx.x < QKVG_BLOCKS) {
    // ================= qkvg body (R19-verified) =================
    float* As = (float*)SMEM;             // 4 KB
    float* Bs = (float*)(SMEM + 4096);    // 4 KB
    float* MU = (float*)(SMEM + 8192);    // 256 B
    float* RS = (float*)(SMEM + 8448);    // 256 B
    float* LW = (float*)(SMEM + 8704);    // 1 KB
    float* LB = (float*)(SMEM + 9728);    // 1 KB
    int fb = blockIdx.x;
    int n0 = (fb & 15) * 64, i0 = (fb >> 4) * 64;
    bool isg = (n0 >= 768);
    const float* W = isg ? wg : wqkv;
    int ldb = isg ? 256 : 768;
    int nc0 = isg ? n0 - 768 : n0;
    int tm = t >> 4, tn = t & 15;
    int sm = t >> 2, sk = (t & 3) * 4;
    int bk = t >> 4, bn = (t & 15) * 4;

    LW[t] = nlnw[t];
    LB[t] = nlnb[t];
    {
      int r = t >> 2, q = t & 3;
      const float4* src = (const float4*)&node[(size_t)(i0 + r) * 256 + q * 64];
      float s1 = 0.f, s2 = 0.f;
#pragma unroll
      for (int c = 0; c < 16; ++c) {
        float4 p = src[c];
        s1 += p.x + p.y + p.z + p.w;
        s2 = fmaf(p.x, p.x, fmaf(p.y, p.y, fmaf(p.z, p.z, fmaf(p.w, p.w, s2))));
      }
      s1 += __shfl_xor(s1, 1); s1 += __shfl_xor(s1, 2);
      s2 += __shfl_xor(s2, 1); s2 += __shfl_xor(s2, 2);
      if (q == 0) {
        float mu = s1 * (1.f / 256.f);
        float var = s2 * (1.f / 256.f) - mu * mu;
        MU[r] = mu;
        RS[r] = rsqrtf(var + 1e-5f);
      }
    }
    __syncthreads();

    float acc[4][4] = {{0.f}};
    for (int k0 = 0; k0 < 256; k0 += 16) {
      float4 av = *(const float4*)&node[(size_t)(i0 + sm) * 256 + k0 + sk];
      float4 bv = *(const float4*)&W[(size_t)(k0 + bk) * ldb + nc0 + bn];
      __syncthreads();
      {
        float mu = MU[sm], rs = RS[sm];
        av.x = (av.x - mu) * rs * LW[k0 + sk + 0] + LB[k0 + sk + 0];
        av.y = (av.y - mu) * rs * LW[k0 + sk + 1] + LB[k0 + sk + 1];
        av.z = (av.z - mu) * rs * LW[k0 + sk + 2] + LB[k0 + sk + 2];
        av.w = (av.w - mu) * rs * LW[k0 + sk + 3] + LB[k0 + sk + 3];
      }
      As[(sk + 0) * 64 + sm] = av.x; As[(sk + 1) * 64 + sm] = av.y;
      As[(sk + 2) * 64 + sm] = av.z; As[(sk + 3) * 64 + sm] = av.w;
      *(float4*)&Bs[bk * 64 + bn] = bv;
      __syncthreads();
#pragma unroll
      for (int kk = 0; kk < 16; ++kk) {
        float4 a4 = *(float4*)&As[kk * 64 + tm * 4];
        float4 b4 = *(float4*)&Bs[kk * 64 + tn * 4];
        float ar[4] = {a4.x, a4.y, a4.z, a4.w};
        float br[4] = {b4.x, b4.y, b4.z, b4.w};
#pragma unroll
        for (int ii = 0; ii < 4; ++ii)
#pragma unroll
          for (int jj = 0; jj < 4; ++jj) acc[ii][jj] = fmaf(ar[ii], br[jj], acc[ii][jj]);
      }
    }
#pragma unroll
    for (int ii = 0; ii < 4; ++ii) {
      int i = i0 + tm * 4 + ii;
#pragma unroll
      for (int jj = 0; jj < 4; ++jj) {
        int o = n0 + tn * 4 + jj;
        float val = acc[ii][jj];
        if (!isg) {
          int which = o >> 8, inner = o & 255, h = inner >> 5, d = inner & 31;
          float* dst = ws + (which == 0 ? WS_Q : (which == 1 ? WS_K : WS_V));
          float sc = (which == 0) ? 0.17677669529663687f : 1.f;  // 1/sqrt(32) on q
          dst[(h * NT + i) * DH + d] = val * sc;
        } else {
          int inner = nc0 + tn * 4 + jj;
          val += bg[inner];
          ws[WS_GATE + i * ND + inner] = 1.f / (1.f + __expf(-val));
        }
      }
    }
  } else {
    // ================= pair_bias body (R16-verified) =================
    int w = t >> 6, l = t & 63;
    int col = l & 15, kg = l >> 4;
    int half = l & 1;
    int ldrow = l >> 5;            // row parity within a load instr
    int gwr = (l & 31) >> 1;       // write granule 0..15
    unsigned short* at = (unsigned short*)SMEM + w * (2 * 16 * 128);

    // build B-frags + c0/c1 in-wave (L2-hot, once per wave)
    bf16x8 bfrag[4];
    float c0p = 0.f, c1p = 0.f;
#pragma unroll
    for (int c = 0; c < 4; ++c) {
#pragma unroll
      for (int e = 0; e < 8; ++e) {
        int k = c * 32 + kg * 8 + e;
        float lw = plnw[k];
        float lb = plnb[k];
        float wv = (col < 8) ? wb[k * 8 + col] : 0.f;
        float wp = lw * wv;
        bfrag[c][e] = (col == 8) ? (short)0x3F80 : f2bf(wp);
        c1p += wp;
        c0p = fmaf(lb, wv, c0p);
      }
    }
    c1p += __shfl_xor(c1p, 16); c1p += __shfl_xor(c1p, 32);
    c0p += __shfl_xor(c0p, 16); c0p += __shfl_xor(c0p, 32);

    size_t pbid = blockIdx.x - QKVG_BLOCKS;
    size_t wrow0 = (pbid * 4 + w) * 64;   // this wave's 64 rows
    int srcl = (l & 48) | 8;              // s1/s2 holder lane in group

    // prefetch tile 0
    f32x4 pin[8];
#pragma unroll
    for (int i = 0; i < 8; ++i)
      pin[i] = *(const f32x4*)(pf + wrow0 * 128 + i * 256 + l * 4);

    for (int tile = 0; tile < 4; ++tile) {
      size_t r0 = wrow0 + tile * 16;
      // convert current tile -> LDS (A and A2)
#pragma unroll
      for (int i = 0; i < 8; ++i) {
        f32x4 p = pin[i];
        int row = i * 2 + ldrow;
        unsigned long long pk = pack4bf(p);
        unsigned long long pk2 = pack4bf(p * p);
        char* base = (char*)at + row * 256 + ((gwr ^ row) * 16) + half * 8;
        *(unsigned long long*)base = pk;
        *(unsigned long long*)(base + 16 * 256) = pk2;   // A2 same layout
      }
      // issue next tile's loads (overlap with MFMA+epilogue below)
      if (tile < 3) {
#pragma unroll
        for (int i = 0; i < 8; ++i)
          pin[i] = *(const f32x4*)(pf + (r0 + 16) * 128 + i * 256 + l * 4);
      }
      // frag reads + 2 MFMA chains over K=128
      f32x4v acc = {0.f, 0.f, 0.f, 0.f};
      f32x4v acc2 = {0.f, 0.f, 0.f, 0.f};
#pragma unroll
      for (int c = 0; c < 4; ++c) {
        const char* rb = (const char*)at + col * 256 + (((c * 4 + kg) ^ col) * 16);
        bf16x8 afrag = *(const bf16x8*)rb;
        bf16x8 afrag2 = *(const bf16x8*)(rb + 16 * 256);
        acc = __builtin_amdgcn_mfma_f32_16x16x32_bf16(afrag, bfrag[c], acc, 0, 0, 0);
        acc2 = __builtin_amdgcn_mfma_f32_16x16x32_bf16(afrag2, bfrag[c], acc2, 0, 0, 0);
      }
      // epilogue: broadcast s1/s2 from col-8 lane, LN transform, fold mask, store
      int4 mk4 = *(const int4*)&mask[r0 + kg * 4];
      float4 ov;
      int mks[4] = {mk4.x, mk4.y, mk4.z, mk4.w};
#pragma unroll
      for (int rg = 0; rg < 4; ++rg) {
        float s1 = __shfl(acc[rg], srcl);
        float s2 = __shfl(acc2[rg], srcl);
        float mu = s1 * (1.f / 128.f);
        float var = s2 * (1.f / 128.f) - mu * mu;
        float rs = rsqrtf(var + 1e-5f);
        float bv = rs * (acc[rg] - mu * c1p) + c0p;
        (&ov.x)[rg] = mks[rg] ? bv : -1e30f;
      }
      if (col < 8) {
        size_t i_idx = r0 / 768;              // tiles never cross an i boundary
        int j0 = (int)(r0 % 768) + kg * 4;
        *(float4*)&bias_out[(i_idx * 8 + col) * 768 + j0] = ov;
      }
    }
  }
}

// ---------------- K4: per (head, 8-row tile) attention + gate ----------------
// v4 (R16-verified): SIM-LDS structure, float4 SIM reads + 4 accumulators.
__global__ __launch_bounds__(256) void k_attn(const float* __restrict__ q,
                                              const float* __restrict__ k,
                                              const float* __restrict__ v,
                                              const float* __restrict__ gate,
                                              const float* __restrict__ bias,
                                              float* __restrict__ aout) {
  __shared__ __align__(16) float SIM[8 * 772];
  __shared__ __align__(16) float QS[256];
  int i0 = blockIdx.x * 8, h = blockIdx.y, t = threadIdx.x;
  int tr = t >> 5, tc = t & 31;
  QS[t] = q[((size_t)h * NT + i0 + tr) * DH + tc];   // t == tr*32+tc
  float4 qr[8];
#pragma unroll
  for (int e = 0; e < 8; ++e) qr[e] = *(float4*)&QS[tr * 32 + e * 4];
  const float* Kh = k + (size_t)h * NT * DH;
  const float* Vh = v + (size_t)h * NT * DH;
  const float* brow = bias + ((size_t)(i0 + tr) * 8 + h) * 768;   // [i][h][j]
  float sv[24];
  float mx = -3.4e38f;
#pragma unroll
  for (int it = 0; it < 24; ++it) {
    int j = it * 32 + tc;
    const float4* kr = (const float4*)(Kh + j * DH);
    float s = 0.f;
#pragma unroll
    for (int e = 0; e < 8; ++e) {
      float4 kv = kr[e];
      s += qr[e].x * kv.x + qr[e].y * kv.y + qr[e].z * kv.z + qr[e].w * kv.w;
    }
    s += brow[j];                     // q pre-scaled; bias carries mask fold
    sv[it] = s;
    mx = fmaxf(mx, s);
  }
#pragma unroll
  for (int m = 1; m < 32; m <<= 1) mx = fmaxf(mx, __shfl_xor(mx, m));
  float sum = 0.f;
#pragma unroll
  for (int it = 0; it < 24; ++it) {
    float p = __expf(sv[it] - mx);
    SIM[tr * 772 + it * 32 + tc] = p;
    sum += p;
  }
#pragma unroll
  for (int m = 1; m < 32; m <<= 1) sum += __shfl_xor(sum, m);
  float inv = 1.f / sum;
  __syncthreads();
  float acc0 = 0.f, acc1 = 0.f, acc2 = 0.f, acc3 = 0.f;
#pragma unroll 4
  for (int j4 = 0; j4 < NT; j4 += 4) {
    float4 p4 = *(float4*)&SIM[tr * 772 + j4];   // b128 broadcast (2 addrs/wave)
    acc0 = fmaf(p4.x, Vh[(j4 + 0) * DH + tc], acc0);
    acc1 = fmaf(p4.y, Vh[(j4 + 1) * DH + tc], acc1);
    acc2 = fmaf(p4.z, Vh[(j4 + 2) * DH + tc], acc2);
    acc3 = fmaf(p4.w, Vh[(j4 + 3) * DH + tc], acc3);
  }
  float acc = ((acc0 + acc1) + (acc2 + acc3)) * inv;
  int i = i0 + tr;
  float gg = gate[i * ND + h * DH + tc];
  aout[i * ND + h * DH + tc] = acc * gg;
}

// ---------------- K5: aout @ w_out + b_out -> fp32 output ----------------
__global__ __launch_bounds__(256) void k_proj(const float* __restrict__ a,
                                              const float* __restrict__ w,
                                              const float* __restrict__ b,
                                              float* __restrict__ out) {
  __shared__ __align__(16) float As[16 * 64];
  __shared__ __align__(16) float Bs[16 * 64];
  int n0 = blockIdx.x * 64, i0 = blockIdx.y * 64, t = threadIdx.x;
  int tm = t >> 4, tn = t & 15;
  int sm = t >> 2, sk = (t & 3) * 4;
  int bk = t >> 4, bn = (t & 15) * 4;
  float acc[4][4] = {{0.f}};
  for (int k0 = 0; k0 < 256; k0 += 16) {
    float4 av = *(const float4*)&a[(i0 + sm) * 256 + k0 + sk];
    float4 bv = *(const float4*)&w[(k0 + bk) * 256 + n0 + bn];
    __syncthreads();
    As[(sk + 0) * 64 + sm] = av.x; As[(sk + 1) * 64 + sm] = av.y;
    As[(sk + 2) * 64 + sm] = av.z; As[(sk + 3) * 64 + sm] = av.w;
    *(float4*)&Bs[bk * 64 + bn] = bv;
    __syncthreads();
#pragma unroll
    for (int kk = 0; kk < 16; ++kk) {
      float4 a4 = *(float4*)&As[kk * 64 + tm * 4];
      float4 b4 = *(float4*)&Bs[kk * 64 + tn * 4];
      float ar[4] = {a4.x, a4.y, a4.z, a4.w};
      float br[4] = {b4.x, b4.y, b4.z, b4.w};
#pragma unroll
      for (int ii = 0; ii < 4; ++ii)
#pragma unroll
        for (int jj = 0; jj < 4; ++jj) acc[ii][jj] = fmaf(ar[ii], br[jj], acc[ii][jj]);
    }
  }
#pragma unroll
  for (int ii = 0; ii < 4; ++ii) {
    int i = i0 + tm * 4 + ii;
#pragma unroll
    for (int jj = 0; jj < 4; ++jj) {
      int o = n0 + tn * 4 + jj;
      out[i * 256 + o] = acc[ii][jj] + b[o];
    }
  }
}

extern "C" void kernel_launch(void* const* d_in, const int* in_sizes, int n_in,
                              void* d_out, int out_size, void* d_ws, size_t ws_size,
                              hipStream_t stream) {
  const float* node   = (const float*)d_in[0];
  const float* pair   = (const float*)d_in[1];
  const int*   mask   = (const int*)d_in[2];
  const float* ln_nw  = (const float*)d_in[3];
  const float* ln_nb  = (const float*)d_in[4];
  const float* ln_pw  = (const float*)d_in[5];
  const float* ln_pb  = (const float*)d_in[6];
  const float* w_qkv  = (const float*)d_in[7];
  const float* w_g    = (const float*)d_in[8];
  const float* b_g    = (const float*)d_in[9];
  const float* w_bias = (const float*)d_in[10];
  const float* w_out  = (const float*)d_in[11];
  const float* b_out  = (const float*)d_in[12];
  float* ws = (float*)d_ws;
  float* out = (float*)d_out;

  k_fused<<<QKVG_BLOCKS + PAIR_BLOCKS, 256, 0, stream>>>(
      node, ln_nw, ln_nb, w_qkv, w_g, b_g, ws,
      pair, mask, ln_pw, ln_pb, w_bias, ws + WS_BIAS);
  k_attn<<<dim3(96, 8), 256, 0, stream>>>(ws + WS_Q, ws + WS_K, ws + WS_V,
                                          ws + WS_GATE, ws + WS_BIAS, ws + WS_AOUT);
  k_proj<<<dim3(4, 12), 256, 0, stream>>>(ws + WS_AOUT, w_out, b_out, out);
}

// Round 22
// 166.131 us; speedup vs baseline: 1.1535x; 1.0127x over previous
//
#include <hip/hip_runtime.h>
#include <hip/hip_bf16.h>

#define NT 768
#define ND 256
#define PD 128
#define NH 8
#define DH 32
#define NPAIR 589824   // 768*768

// workspace offsets (floats)
#define WS_X     0
#define WS_Q     196608
#define WS_K     393216
#define WS_V     589824
#define WS_GATE  786432
#define WS_AOUT  983040
#define WS_BIAS  1179648   // bias layout: [i][h][j] = (i*8+h)*768+j
// total = 1179648 + 8*589824 = 5898240 floats = 23.6 MB

#define QKVG_BLOCKS 192    // 16 x 12
#define PAIR_BLOCKS 2304   // NPAIR/256

typedef float f32x4 __attribute__((ext_vector_type(4)));
using bf16x8 = __attribute__((ext_vector_type(8))) short;   // 8 bf16 (4 VGPR)
using f32x4v = __attribute__((ext_vector_type(4))) float;

// compiler-fusable bf16 cast (emits v_cvt_pk_bf16_f32 for pairs — m240)
static __device__ __forceinline__ short f2bf(float f) {
  union { __hip_bfloat16 h; short s; } u;
  u.h = __float2bfloat16(f);
  return u.s;
}
static __device__ __forceinline__ unsigned long long pack4bf(f32x4 p) {
  return (unsigned long long)(unsigned short)f2bf(p.x) |
         ((unsigned long long)(unsigned short)f2bf(p.y) << 16) |
         ((unsigned long long)(unsigned short)f2bf(p.z) << 32) |
         ((unsigned long long)(unsigned short)f2bf(p.w) << 48);
}

// ---------------- K1 fused: [qkvg blocks 0..191] + [pair_bias blocks 192..2495] ----------------
__global__ __launch_bounds__(256) void k_fused(
    const float* __restrict__ node, const float* __restrict__ nlnw,
    const float* __restrict__ nlnb, const float* __restrict__ wqkv,
    const float* __restrict__ wg, const float* __restrict__ bg,
    float* __restrict__ ws,
    const float* __restrict__ pf, const int* __restrict__ mask,
    const float* __restrict__ plnw, const float* __restrict__ plnb,
    const float* __restrict__ wb, float* __restrict__ bias_out) {
  __shared__ __align__(16) char SMEM[32768];
  int t = threadIdx.x;

  if (blockIdx.x < QKVG_BLOCKS) {
    // ================= qkvg body (R19-verified) =================
    float* As = (float*)SMEM;             // 4 KB
    float* Bs = (float*)(SMEM + 4096);    // 4 KB
    float* MU = (float*)(SMEM + 8192);    // 256 B
    float* RS = (float*)(SMEM + 8448);    // 256 B
    float* LW = (float*)(SMEM + 8704);    // 1 KB
    float* LB = (float*)(SMEM + 9728);    // 1 KB
    int fb = blockIdx.x;
    int n0 = (fb & 15) * 64, i0 = (fb >> 4) * 64;
    bool isg = (n0 >= 768);
    const float* W = isg ? wg : wqkv;
    int ldb = isg ? 256 : 768;
    int nc0 = isg ? n0 - 768 : n0;
    int tm = t >> 4, tn = t & 15;
    int sm = t >> 2, sk = (t & 3) * 4;
    int bk = t >> 4, bn = (t & 15) * 4;

    LW[t] = nlnw[t];
    LB[t] = nlnb[t];
    {
      int r = t >> 2, q = t & 3;
      const float4* src = (const float4*)&node[(size_t)(i0 + r) * 256 + q * 64];
      float s1 = 0.f, s2 = 0.f;
#pragma unroll
      for (int c = 0; c < 16; ++c) {
        float4 p = src[c];
        s1 += p.x + p.y + p.z + p.w;
        s2 = fmaf(p.x, p.x, fmaf(p.y, p.y, fmaf(p.z, p.z, fmaf(p.w, p.w, s2))));
      }
      s1 += __shfl_xor(s1, 1); s1 += __shfl_xor(s1, 2);
      s2 += __shfl_xor(s2, 1); s2 += __shfl_xor(s2, 2);
      if (q == 0) {
        float mu = s1 * (1.f / 256.f);
        float var = s2 * (1.f / 256.f) - mu * mu;
        MU[r] = mu;
        RS[r] = rsqrtf(var + 1e-5f);
      }
    }
    __syncthreads();

    float acc[4][4] = {{0.f}};
    for (int k0 = 0; k0 < 256; k0 += 16) {
      float4 av = *(const float4*)&node[(size_t)(i0 + sm) * 256 + k0 + sk];
      float4 bv = *(const float4*)&W[(size_t)(k0 + bk) * ldb + nc0 + bn];
      __syncthreads();
      {
        float mu = MU[sm], rs = RS[sm];
        av.x = (av.x - mu) * rs * LW[k0 + sk + 0] + LB[k0 + sk + 0];
        av.y = (av.y - mu) * rs * LW[k0 + sk + 1] + LB[k0 + sk + 1];
        av.z = (av.z - mu) * rs * LW[k0 + sk + 2] + LB[k0 + sk + 2];
        av.w = (av.w - mu) * rs * LW[k0 + sk + 3] + LB[k0 + sk + 3];
      }
      As[(sk + 0) * 64 + sm] = av.x; As[(sk + 1) * 64 + sm] = av.y;
      As[(sk + 2) * 64 + sm] = av.z; As[(sk + 3) * 64 + sm] = av.w;
      *(float4*)&Bs[bk * 64 + bn] = bv;
      __syncthreads();
#pragma unroll
      for (int kk = 0; kk < 16; ++kk) {
        float4 a4 = *(float4*)&As[kk * 64 + tm * 4];
        float4 b4 = *(float4*)&Bs[kk * 64 + tn * 4];
        float ar[4] = {a4.x, a4.y, a4.z, a4.w};
        float br[4] = {b4.x, b4.y, b4.z, b4.w};
#pragma unroll
        for (int ii = 0; ii < 4; ++ii)
#pragma unroll
          for (int jj = 0; jj < 4; ++jj) acc[ii][jj] = fmaf(ar[ii], br[jj], acc[ii][jj]);
      }
    }
#pragma unroll
    for (int ii = 0; ii < 4; ++ii) {
      int i = i0 + tm * 4 + ii;
#pragma unroll
      for (int jj = 0; jj < 4; ++jj) {
        int o = n0 + tn * 4 + jj;
        float val = acc[ii][jj];
        if (!isg) {
          int which = o >> 8, inner = o & 255, h = inner >> 5, d = inner & 31;
          float* dst = ws + (which == 0 ? WS_Q : (which == 1 ? WS_K : WS_V));
          float sc = (which == 0) ? 0.17677669529663687f : 1.f;  // 1/sqrt(32) on q
          dst[(h * NT + i) * DH + d] = val * sc;
        } else {
          int inner = nc0 + tn * 4 + jj;
          val += bg[inner];
          ws[WS_GATE + i * ND + inner] = 1.f / (1.f + __expf(-val));
        }
      }
    }
  } else {
    // ================= pair_bias body (R16-verified) =================
    int w = t >> 6, l = t & 63;
    int col = l & 15, kg = l >> 4;
    int half = l & 1;
    int ldrow = l >> 5;            // row parity within a load instr
    int gwr = (l & 31) >> 1;       // write granule 0..15
    unsigned short* at = (unsigned short*)SMEM + w * (2 * 16 * 128);

    // build B-frags + c0/c1 in-wave (L2-hot, once per wave)
    bf16x8 bfrag[4];
    float c0p = 0.f, c1p = 0.f;
#pragma unroll
    for (int c = 0; c < 4; ++c) {
#pragma unroll
      for (int e = 0; e < 8; ++e) {
        int k = c * 32 + kg * 8 + e;
        float lw = plnw[k];
        float lb = plnb[k];
        float wv = (col < 8) ? wb[k * 8 + col] : 0.f;
        float wp = lw * wv;
        bfrag[c][e] = (col == 8) ? (short)0x3F80 : f2bf(wp);
        c1p += wp;
        c0p = fmaf(lb, wv, c0p);
      }
    }
    c1p += __shfl_xor(c1p, 16); c1p += __shfl_xor(c1p, 32);
    c0p += __shfl_xor(c0p, 16); c0p += __shfl_xor(c0p, 32);

    size_t pbid = blockIdx.x - QKVG_BLOCKS;
    size_t wrow0 = (pbid * 4 + w) * 64;   // this wave's 64 rows
    int srcl = (l & 48) | 8;              // s1/s2 holder lane in group

    // prefetch tile 0
    f32x4 pin[8];
#pragma unroll
    for (int i = 0; i < 8; ++i)
      pin[i] = *(const f32x4*)(pf + wrow0 * 128 + i * 256 + l * 4);

    for (int tile = 0; tile < 4; ++tile) {
      size_t r0 = wrow0 + tile * 16;
      // convert current tile -> LDS (A and A2)
#pragma unroll
      for (int i = 0; i < 8; ++i) {
        f32x4 p = pin[i];
        int row = i * 2 + ldrow;
        unsigned long long pk = pack4bf(p);
        unsigned long long pk2 = pack4bf(p * p);
        char* base = (char*)at + row * 256 + ((gwr ^ row) * 16) + half * 8;
        *(unsigned long long*)base = pk;
        *(unsigned long long*)(base + 16 * 256) = pk2;   // A2 same layout
      }
      // issue next tile's loads (overlap with MFMA+epilogue below)
      if (tile < 3) {
#pragma unroll
        for (int i = 0; i < 8; ++i)
          pin[i] = *(const f32x4*)(pf + (r0 + 16) * 128 + i * 256 + l * 4);
      }
      // frag reads + 2 MFMA chains over K=128
      f32x4v acc = {0.f, 0.f, 0.f, 0.f};
      f32x4v acc2 = {0.f, 0.f, 0.f, 0.f};
#pragma unroll
      for (int c = 0; c < 4; ++c) {
        const char* rb = (const char*)at + col * 256 + (((c * 4 + kg) ^ col) * 16);
        bf16x8 afrag = *(const bf16x8*)rb;
        bf16x8 afrag2 = *(const bf16x8*)(rb + 16 * 256);
        acc = __builtin_amdgcn_mfma_f32_16x16x32_bf16(afrag, bfrag[c], acc, 0, 0, 0);
        acc2 = __builtin_amdgcn_mfma_f32_16x16x32_bf16(afrag2, bfrag[c], acc2, 0, 0, 0);
      }
      // epilogue: broadcast s1/s2 from col-8 lane, LN transform, fold mask, store
      int4 mk4 = *(const int4*)&mask[r0 + kg * 4];
      float4 ov;
      int mks[4] = {mk4.x, mk4.y, mk4.z, mk4.w};
#pragma unroll
      for (int rg = 0; rg < 4; ++rg) {
        float s1 = __shfl(acc[rg], srcl);
        float s2 = __shfl(acc2[rg], srcl);
        float mu = s1 * (1.f / 128.f);
        float var = s2 * (1.f / 128.f) - mu * mu;
        float rs = rsqrtf(var + 1e-5f);
        float bv = rs * (acc[rg] - mu * c1p) + c0p;
        (&ov.x)[rg] = mks[rg] ? bv : -1e30f;
      }
      if (col < 8) {
        size_t i_idx = r0 / 768;              // tiles never cross an i boundary
        int j0 = (int)(r0 % 768) + kg * 4;
        *(float4*)&bias_out[(i_idx * 8 + col) * 768 + j0] = ov;
      }
    }
  }
}

// ---------------- K4: per (head, 8-row tile) attention + gate ----------------
// v5: QK unchanged; PV remapped to (jg = tc>>3, dq = tc&7): float4 V loads
// (192 vs 768 scalar), scalar SIM broadcast reads, f32x4 accumulate,
// 8-shuffle cross-jg reduce, float4 gated store by lanes jg==0.
__global__ __launch_bounds__(256) void k_attn(const float* __restrict__ q,
                                              const float* __restrict__ k,
                                              const float* __restrict__ v,
                                              const float* __restrict__ gate,
                                              const float* __restrict__ bias,
                                              float* __restrict__ aout) {
  __shared__ __align__(16) float SIM[8 * 772];
  __shared__ __align__(16) float QS[256];
  int i0 = blockIdx.x * 8, h = blockIdx.y, t = threadIdx.x;
  int tr = t >> 5, tc = t & 31;
  QS[t] = q[((size_t)h * NT + i0 + tr) * DH + tc];   // t == tr*32+tc
  float4 qr[8];
#pragma unroll
  for (int e = 0; e < 8; ++e) qr[e] = *(float4*)&QS[tr * 32 + e * 4];
  const float* Kh = k + (size_t)h * NT * DH;
  const float* Vh = v + (size_t)h * NT * DH;
  const float* brow = bias + ((size_t)(i0 + tr) * 8 + h) * 768;   // [i][h][j]
  float sv[24];
  float mx = -3.4e38f;
#pragma unroll
  for (int it = 0; it < 24; ++it) {
    int j = it * 32 + tc;
    const float4* kr = (const float4*)(Kh + j * DH);
    float s = 0.f;
#pragma unroll
    for (int e = 0; e < 8; ++e) {
      float4 kv = kr[e];
      s += qr[e].x * kv.x + qr[e].y * kv.y + qr[e].z * kv.z + qr[e].w * kv.w;
    }
    s += brow[j];                     // q pre-scaled; bias carries mask fold
    sv[it] = s;
    mx = fmaxf(mx, s);
  }
#pragma unroll
  for (int m = 1; m < 32; m <<= 1) mx = fmaxf(mx, __shfl_xor(mx, m));
  float sum = 0.f;
#pragma unroll
  for (int it = 0; it < 24; ++it) {
    float p = __expf(sv[it] - mx);
    SIM[tr * 772 + it * 32 + tc] = p;
    sum += p;
  }
#pragma unroll
  for (int m = 1; m < 32; m <<= 1) sum += __shfl_xor(sum, m);
  float inv = 1.f / sum;
  __syncthreads();
  // PV v5: lane (jg, dq) covers j = it*4+jg, dims dq*4..+3
  int dq = tc & 7, jg = tc >> 3;
  f32x4 acc4 = {0.f, 0.f, 0.f, 0.f};
#pragma unroll 8
  for (int it = 0; it < 192; ++it) {
    int j = it * 4 + jg;
    float p = SIM[tr * 772 + j];              // 4 addrs/row, broadcast to 8 lanes
    f32x4 v4 = *(const f32x4*)(Vh + j * DH + dq * 4);   // 128B contiguous per jg
    f32x4 pv = {p, p, p, p};
    acc4 = __builtin_elementwise_fma(pv, v4, acc4);
  }
  // reduce across the 4 jg groups (tc bits 3,4)
#pragma unroll
  for (int m = 8; m <= 16; m <<= 1) {
    f32x4 o;
    o.x = __shfl_xor(acc4.x, m); o.y = __shfl_xor(acc4.y, m);
    o.z = __shfl_xor(acc4.z, m); o.w = __shfl_xor(acc4.w, m);
    acc4 += o;
  }
  if (jg == 0) {
    int i = i0 + tr;
    f32x4 g4 = *(const f32x4*)(gate + i * ND + h * DH + dq * 4);
    f32x4 r = acc4 * inv * g4;
    *(f32x4*)(aout + i * ND + h * DH + dq * 4) = r;
  }
}

// ---------------- K5: aout @ w_out + b_out -> fp32 output ----------------
__global__ __launch_bounds__(256) void k_proj(const float* __restrict__ a,
                                              const float* __restrict__ w,
                                              const float* __restrict__ b,
                                              float* __restrict__ out) {
  __shared__ __align__(16) float As[16 * 64];
  __shared__ __align__(16) float Bs[16 * 64];
  int n0 = blockIdx.x * 64, i0 = blockIdx.y * 64, t = threadIdx.x;
  int tm = t >> 4, tn = t & 15;
  int sm = t >> 2, sk = (t & 3) * 4;
  int bk = t >> 4, bn = (t & 15) * 4;
  float acc[4][4] = {{0.f}};
  for (int k0 = 0; k0 < 256; k0 += 16) {
    float4 av = *(const float4*)&a[(i0 + sm) * 256 + k0 + sk];
    float4 bv = *(const float4*)&w[(k0 + bk) * 256 + n0 + bn];
    __syncthreads();
    As[(sk + 0) * 64 + sm] = av.x; As[(sk + 1) * 64 + sm] = av.y;
    As[(sk + 2) * 64 + sm] = av.z; As[(sk + 3) * 64 + sm] = av.w;
    *(float4*)&Bs[bk * 64 + bn] = bv;
    __syncthreads();
#pragma unroll
    for (int kk = 0; kk < 16; ++kk) {
      float4 a4 = *(float4*)&As[kk * 64 + tm * 4];
      float4 b4 = *(float4*)&Bs[kk * 64 + tn * 4];
      float ar[4] = {a4.x, a4.y, a4.z, a4.w};
      float br[4] = {b4.x, b4.y, b4.z, b4.w};
#pragma unroll
      for (int ii = 0; ii < 4; ++ii)
#pragma unroll
        for (int jj = 0; jj < 4; ++jj) acc[ii][jj] = fmaf(ar[ii], br[jj], acc[ii][jj]);
    }
  }
#pragma unroll
  for (int ii = 0; ii < 4; ++ii) {
    int i = i0 + tm * 4 + ii;
#pragma unroll
    for (int jj = 0; jj < 4; ++jj) {
      int o = n0 + tn * 4 + jj;
      out[i * 256 + o] = acc[ii][jj] + b[o];
    }
  }
}

extern "C" void kernel_launch(void* const* d_in, const int* in_sizes, int n_in,
                              void* d_out, int out_size, void* d_ws, size_t ws_size,
                              hipStream_t stream) {
  const float* node   = (const float*)d_in[0];
  const float* pair   = (const float*)d_in[1];
  const int*   mask   = (const int*)d_in[2];
  const float* ln_nw  = (const float*)d_in[3];
  const float* ln_nb  = (const float*)d_in[4];
  const float* ln_pw  = (const float*)d_in[5];
  const float* ln_pb  = (const float*)d_in[6];
  const float* w_qkv  = (const float*)d_in[7];
  const float* w_g    = (const float*)d_in[8];
  const float* b_g    = (const float*)d_in[9];
  const float* w_bias = (const float*)d_in[10];
  const float* w_out  = (const float*)d_in[11];
  const float* b_out  = (const float*)d_in[12];
  float* ws = (float*)d_ws;
  float* out = (float*)d_out;

  k_fused<<<QKVG_BLOCKS + PAIR_BLOCKS, 256, 0, stream>>>(
      node, ln_nw, ln_nb, w_qkv, w_g, b_g, ws,
      pair, mask, ln_pw, ln_pb, w_bias, ws + WS_BIAS);
  k_attn<<<dim3(96, 8), 256, 0, stream>>>(ws + WS_Q, ws + WS_K, ws + WS_V,
                                          ws + WS_GATE, ws + WS_BIAS, ws + WS_AOUT);
  k_proj<<<dim3(4, 12), 256, 0, stream>>>(ws + WS_AOUT, w_out, b_out, out);
}